// Round 11
// baseline (306.490 us; speedup 1.0000x reference)
//
#include <hip/hip_runtime.h>
#include <cstdint>
#include <cmath>

#define DIM   768
#define HID   3072
#define NEXP  8
#define DLOW  192
#define NPB   1024            // tokens per image (32*32)
#define NTOK  8192
#define KD    1536            // NEXP*DLOW
#define KCAT  4608            // HID + KD

typedef unsigned short ushort_t;
typedef short   short8  __attribute__((ext_vector_type(8)));
typedef float   float4v __attribute__((ext_vector_type(4)));

__device__ inline ushort_t f2b(float f) {
    union { float f; unsigned int i; } v; v.f = f;
    unsigned int x = v.i;
    return (ushort_t)((x + 0x7fffu + ((x >> 16) & 1u)) >> 16);   // RNE
}
// tanh-form GELU (max |err| vs erf-GELU ~3e-4, below bf16 rounding of HU)
__device__ inline float gelu_fast(float x) {
    const float z = 1.5957691216057308f * x * __builtin_fmaf(0.044715f * x, x, 1.0f);
    return x * __builtin_amdgcn_rcpf(1.0f + __expf(-z));
}

// async global->LDS, 16 B per lane (global_load_lds_dwordx4)
__device__ __forceinline__ void async_ld16(const ushort_t* g, ushort_t* l) {
    __builtin_amdgcn_global_load_lds(
        (const __attribute__((address_space(1))) void*)g,
        (__attribute__((address_space(3))) void*)l,
        16, 0, 0);
}

// ===========================================================================
// Counted-vmcnt dbuf K-loop (T4) -- verified r9/r10. r11 adds kh-half
// REGISTER PREFETCH to gemm_in: each ds_read batch now completes UNDER 16
// independent MFMAs of the previous half (r10 counters: LDS floor 34.5us,
// MFMA 28us, measured 77.5us -> intra-wave serialization was the gap).
// Sync skeleton (2 barriers/body, stage t+2, vmcnt(8) retires t+1) is
// bitwise-identical to the verified r10 kernel.
// ===========================================================================

// ---------------------------------------------------------------------------
// INPUT GEMM v10: 128x128 tile, 256 threads (4 waves 2Mx2N, wave 64x64),
// BK=64, m-inner/n-outer XCD mapping (r10-verified: FETCH 53MB = 8x Win).
// Body t: {read kh1(t) || MFMA kh0(t)} -> lgkm0+bar (buf free) ->
// stage(t+2)+vmcnt(8)+bar (tile t+1 certified) -> {read kh0(t+1) || MFMA
// kh1(t)}. MFMA order unchanged -> numerically identical to r10.
// ---------------------------------------------------------------------------
__global__ __launch_bounds__(256, 2)
void gemm_in(const ushort_t* __restrict__ A, const ushort_t* __restrict__ B,
             ushort_t* __restrict__ Cb, const float* __restrict__ bias,
             const int* __restrict__ tokE, const float* __restrict__ tokW,
             const float* __restrict__ accbuf, float* __restrict__ outAux,
             int m_base)
{
    __shared__ __align__(16) ushort_t As[2 * 128 * 64];   // 32 KB (dbuf)
    __shared__ __align__(16) ushort_t Bs[2 * 128 * 64];   // 32 KB (dbuf)

    const int tid  = threadIdx.x;
    const int lane = tid & 63;
    const int wave = tid >> 6;           // 0..3
    const int quad = lane >> 4;
    const int l16  = lane & 15;
    const int wm   = (wave >> 1) * 64;   // 0,64
    const int wn   = (wave & 1) * 64;    // 0,64

    // XCD mapping, m-inner/n-outer (bijective: gridDim.y multiple of 8)
    const int bid = blockIdx.y * gridDim.x + blockIdx.x;
    const int mpx = gridDim.y >> 3;                // m-panels per XCD
    const int xcd = bid & 7;
    const int loc = bid >> 3;                      // [0, 36*mpx)
    const int m0  = (xcd * mpx + loc % mpx) * 128;
    const int n0  = (loc / mpx) * 128;

    float4v acc[4][4];
#pragma unroll
    for (int i = 0; i < 4; i++)
#pragma unroll
        for (int j = 0; j < 4; j++) acc[i][j] = (float4v)0.0f;

    // staging: LDS slot f holds k-group (f&7)^(row&7) of row f>>3
    const ushort_t* ga[4]; ushort_t* la[4];
#pragma unroll
    for (int j = 0; j < 4; j++) {
        const int f = j * 256 + tid;               // [0, 1024)
        const int mm = f >> 3;                     // [0, 128)
        const int gs = ((f & 7) ^ (mm & 7)) * 8;
        ga[j] = A + (size_t)(m0 + mm) * DIM + gs;
        la[j] = &As[f * 8];
    }
    const ushort_t* gb[4]; ushort_t* lb[4];
#pragma unroll
    for (int j = 0; j < 4; j++) {
        const int f = j * 256 + tid;               // [0, 1024)
        const int mm = f >> 3;                     // [0, 128)
        const int gs = ((f & 7) ^ (mm & 7)) * 8;
        gb[j] = B + (size_t)(n0 + mm) * DIM + gs;
        lb[j] = &Bs[f * 8];
    }

    // fragment LDS pointers (buffer 0; buffer 1 = +128*64 elements)
    const ushort_t* pa[2][4]; const ushort_t* pb[2][4];
#pragma unroll
    for (int kh = 0; kh < 2; kh++)
#pragma unroll
        for (int i = 0; i < 4; i++) {
            const int ra = wm + i * 16 + l16;
            pa[kh][i] = &As[ra * 64 + (((quad + 4 * kh) ^ (ra & 7)) * 8)];
            const int rb = wn + i * 16 + l16;
            pb[kh][i] = &Bs[rb * 64 + (((quad + 4 * kh) ^ (rb & 7)) * 8)];
        }

#define STG_I(k0, ao, bo) do {                                              \
    _Pragma("unroll")                                                       \
    for (int j = 0; j < 4; j++) async_ld16(ga[j] + (k0), la[j] + (ao));     \
    _Pragma("unroll")                                                       \
    for (int j = 0; j < 4; j++) async_ld16(gb[j] + (k0), lb[j] + (bo)); } while (0)

    // two kh half-sets of fragment registers (slot reused across tiles)
    short8 afH[2][4], bvH[2][4];

    // prologue: stage tiles 0,1; certify tile 0; read tile0 kh0
    STG_I(0, 0, 0);
    STG_I(64, 128 * 64, 128 * 64);
    asm volatile("s_waitcnt vmcnt(8)" ::: "memory");   // tile0 landed
    __builtin_amdgcn_s_barrier();
    __builtin_amdgcn_sched_barrier(0);
#pragma unroll
    for (int i = 0; i < 4; i++) {
        afH[0][i] = *(const short8*)(pa[0][i]);
        bvH[0][i] = *(const short8*)(pb[0][i]);
    }

#pragma unroll
    for (int t = 0; t < 12; ++t) {
        const int co = (t & 1) * (128 * 64);        // current buffer
        const int no = ((t + 1) & 1) * (128 * 64);  // next buffer

        // 1. read tile-t kh1 (overlaps MFMA kh0 below)
#pragma unroll
        for (int i = 0; i < 4; i++) {
            afH[1][i] = *(const short8*)(pa[1][i] + co);
            bvH[1][i] = *(const short8*)(pb[1][i] + co);
        }
        // 2. MFMA kh0 (regs from previous body / prologue)
#pragma unroll
        for (int im = 0; im < 4; im++)
#pragma unroll
            for (int in = 0; in < 4; in++)
                acc[im][in] = __builtin_amdgcn_mfma_f32_16x16x32_bf16(
                    afH[0][im], bvH[0][in], acc[im][in], 0, 0, 0);
        // 3. all tile-t reads done -> current buffer free
        asm volatile("s_waitcnt lgkmcnt(0)" ::: "memory");
        __builtin_amdgcn_sched_barrier(0);
        __builtin_amdgcn_s_barrier();
        __builtin_amdgcn_sched_barrier(0);
        // 4. stage t+2 into current buffer; retire tile t+1
        if (t + 2 < 12) {
            STG_I((t + 2) * 64, co, co);
            asm volatile("s_waitcnt vmcnt(8)" ::: "memory");
        } else {
            asm volatile("s_waitcnt vmcnt(0)" ::: "memory");
        }
        __builtin_amdgcn_sched_barrier(0);
        __builtin_amdgcn_s_barrier();           // tile t+1 visible to all
        __builtin_amdgcn_sched_barrier(0);
        // 6. read tile-(t+1) kh0 (overlaps MFMA kh1 below)
        if (t + 1 < 12) {
#pragma unroll
            for (int i = 0; i < 4; i++) {
                afH[0][i] = *(const short8*)(pa[0][i] + no);
                bvH[0][i] = *(const short8*)(pb[0][i] + no);
            }
        }
        // 7. MFMA kh1
#pragma unroll
        for (int im = 0; im < 4; im++)
#pragma unroll
            for (int in = 0; in < 4; in++)
                acc[im][in] = __builtin_amdgcn_mfma_f32_16x16x32_bf16(
                    afH[1][im], bvH[1][in], acc[im][in], 0, 0, 0);
    }
#undef STG_I

    if (n0 < HID) {                        // shared-expert hidden: gelu + b1
#pragma unroll
        for (int in = 0; in < 4; in++) {
            const int col = n0 + wn + in * 16 + l16;
            const float bvv = bias[col];
#pragma unroll
            for (int im = 0; im < 4; im++) {
                const int rowl = m0 + wm + im * 16 + quad * 4;
#pragma unroll
                for (int r = 0; r < 4; r++)
                    Cb[(size_t)(rowl + r) * KCAT + col] =
                        f2b(gelu_fast(acc[im][in][r] + bvv));
            }
        }
        if (m_base == 0 && blockIdx.x == 0 && blockIdx.y == 0 && tid == 0) {
            float aux = 0.0f;
            for (int e = 0; e < 8; e++) aux += accbuf[e] * accbuf[8 + e];
            outAux[0] = aux * 8.0f / ((float)NTOK * (float)NTOK);
        }
    } else {                               // feats: gelu * routing weight
        int eidx[4];
#pragma unroll
        for (int in = 0; in < 4; in++)
            eidx[in] = (n0 + wn + in * 16 - HID) / DLOW;   // uniform over l16
#pragma unroll
        for (int im = 0; im < 4; im++) {
            const int rowl = m0 + wm + im * 16 + quad * 4;
#pragma unroll
            for (int r = 0; r < 4; r++) {
                const int g = m_base + rowl + r;
                const int e0 = tokE[2 * g], e1 = tokE[2 * g + 1];
                const float w0 = tokW[2 * g], w1 = tokW[2 * g + 1];
#pragma unroll
                for (int in = 0; in < 4; in++) {
                    const int col = n0 + wn + in * 16 + l16;
                    const float m = (eidx[in] == e0) ? w0
                                  : ((eidx[in] == e1) ? w1 : 0.0f);
                    Cb[(size_t)(rowl + r) * KCAT + col] =
                        f2b(gelu_fast(acc[im][in][r]) * m);
                }
            }
        }
    }
}

// ---------------------------------------------------------------------------
// OUTPUT GEMM v8 (UNCHANGED -- session best): 128x96 tile, 4 waves 2Mx2N,
// BK=64 counted-vmcnt dbuf, 56 KB LDS, XCD-chunked swizzle.
//   out[b, col, nn] = HU[m,:].Wcat[col,:] + b2[col] + x[b, col, nn]
// ---------------------------------------------------------------------------
__global__ __launch_bounds__(256, 2)
void gemm_out(const ushort_t* __restrict__ A, const ushort_t* __restrict__ B,
              float* __restrict__ out, const float* __restrict__ bias,
              const float* __restrict__ X, int m_base)
{
    __shared__ __align__(16) ushort_t As[2 * 128 * 64];   // 32 KB (dbuf)
    __shared__ __align__(16) ushort_t Bs[2 * 96 * 64];    // 24 KB (dbuf)

    const int tid  = threadIdx.x;
    const int lane = tid & 63;
    const int wave = tid >> 6;           // 0..3
    const int quad = lane >> 4;
    const int l16  = lane & 15;
    const int wm   = (wave >> 1) * 64;   // 0,64
    const int wn   = (wave & 1) * 48;    // 0,48

    // XCD-chunked swizzle (bijective: grid always a multiple of 8)
    const int nwg = gridDim.x * gridDim.y;
    const int bid = blockIdx.y * gridDim.x + blockIdx.x;
    const int swz = (bid & 7) * (nwg >> 3) + (bid >> 3);
    const int m0  = (swz / gridDim.x) * 128;
    const int n0  = (swz % gridDim.x) * 96;

    float4v acc[4][3];
#pragma unroll
    for (int i = 0; i < 4; i++)
#pragma unroll
        for (int j = 0; j < 3; j++) acc[i][j] = (float4v)0.0f;

    // staging: LDS slot f holds k-group (f&7)^(row&7) of row f>>3
    const ushort_t* ga[4]; ushort_t* la[4];
#pragma unroll
    for (int j = 0; j < 4; j++) {
        const int f = j * 256 + tid;               // [0, 1024)
        const int mm = f >> 3;                     // [0, 128)
        const int gs = ((f & 7) ^ (mm & 7)) * 8;
        ga[j] = A + (size_t)(m0 + mm) * KCAT + gs;
        la[j] = &As[f * 8];
    }
    const ushort_t* gb[3]; ushort_t* lb[3];
#pragma unroll
    for (int j = 0; j < 3; j++) {
        const int f = j * 256 + tid;               // [0, 768)
        const int mm = f >> 3;                     // [0, 96)
        const int gs = ((f & 7) ^ (mm & 7)) * 8;
        gb[j] = B + (size_t)(n0 + mm) * KCAT + gs;
        lb[j] = &Bs[f * 8];
    }

    // fragment LDS pointers (buffer 0; buffer 1 = +const element offset)
    const ushort_t* pa[2][4]; const ushort_t* pb[2][3];
#pragma unroll
    for (int kh = 0; kh < 2; kh++) {
#pragma unroll
        for (int i = 0; i < 4; i++) {
            const int ra = wm + i * 16 + l16;
            pa[kh][i] = &As[ra * 64 + (((quad + 4 * kh) ^ (ra & 7)) * 8)];
        }
#pragma unroll
        for (int i = 0; i < 3; i++) {
            const int rb = wn + i * 16 + l16;
            pb[kh][i] = &Bs[rb * 64 + (((quad + 4 * kh) ^ (rb & 7)) * 8)];
        }
    }

#define STG_O(k0, ao, bo) do {                                              \
    _Pragma("unroll")                                                       \
    for (int j = 0; j < 4; j++) async_ld16(ga[j] + (k0), la[j] + (ao));     \
    _Pragma("unroll")                                                       \
    for (int j = 0; j < 3; j++) async_ld16(gb[j] + (k0), lb[j] + (bo)); } while (0)

#define BODY_O(t, ao, bo) do {                                              \
    short8 af0[4], bv0[3], af1[4], bv1[3];                                  \
    _Pragma("unroll")                                                       \
    for (int i = 0; i < 4; i++) {                                           \
        af0[i] = *(const short8*)(pa[0][i] + (ao));                         \
        af1[i] = *(const short8*)(pa[1][i] + (ao));                         \
    }                                                                       \
    _Pragma("unroll")                                                       \
    for (int i = 0; i < 3; i++) {                                           \
        bv0[i] = *(const short8*)(pb[0][i] + (bo));                         \
        bv1[i] = *(const short8*)(pb[1][i] + (bo));                         \
    }                                                                       \
    asm volatile("s_waitcnt lgkmcnt(0)" ::: "memory");                      \
    __builtin_amdgcn_sched_barrier(0);                                      \
    __builtin_amdgcn_s_barrier();          /* all waves done reading buf */ \
    __builtin_amdgcn_sched_barrier(0);     /* no hoist above barrier */     \
    const bool st_ = (t) + 2 < 72;                                          \
    if (st_) STG_O(((t) + 2) * 64, ao, bo);                                 \
    __builtin_amdgcn_s_setprio(1);                                          \
    _Pragma("unroll")                                                       \
    for (int im = 0; im < 4; im++)                                          \
        _Pragma("unroll")                                                   \
        for (int in = 0; in < 3; in++)                                      \
            acc[im][in] = __builtin_amdgcn_mfma_f32_16x16x32_bf16(          \
                af0[im], bv0[in], acc[im][in], 0, 0, 0);                    \
    _Pragma("unroll")                                                       \
    for (int im = 0; im < 4; im++)                                          \
        _Pragma("unroll")                                                   \
        for (int in = 0; in < 3; in++)                                      \
            acc[im][in] = __builtin_amdgcn_mfma_f32_16x16x32_bf16(          \
                af1[im], bv1[in], acc[im][in], 0, 0, 0);                    \
    __builtin_amdgcn_s_setprio(0);                                          \
    if (st_) asm volatile("s_waitcnt vmcnt(7)" ::: "memory");               \
    else     asm volatile("s_waitcnt vmcnt(0)" ::: "memory");               \
    __builtin_amdgcn_sched_barrier(0);                                      \
    __builtin_amdgcn_s_barrier();          /* next tile globally ready */   \
    __builtin_amdgcn_sched_barrier(0);                                      \
} while (0)

    // prologue: stage tiles 0,1; wait own tile-0 loads; sync
    STG_O(0, 0, 0);
    STG_O(64, 128 * 64, 96 * 64);
    asm volatile("s_waitcnt vmcnt(7)" ::: "memory");
    __builtin_amdgcn_s_barrier();
    __builtin_amdgcn_sched_barrier(0);

    for (int tt = 0; tt < 72; tt += 2) {
        BODY_O(tt, 0, 0);
        BODY_O(tt + 1, 128 * 64, 96 * 64);
    }
#undef STG_O
#undef BODY_O

#pragma unroll
    for (int in = 0; in < 3; in++) {
        const int col = n0 + wn + in * 16 + l16;
        const float bvv = bias[col];
#pragma unroll
        for (int im = 0; im < 4; im++) {
            const int grow = m_base + m0 + wm + im * 16 + quad * 4;
            const int bb = grow >> 10, nn = grow & 1023;
            const size_t base = ((size_t)bb * DIM + col) * NPB + nn;
            const float4 xv = *(const float4*)(X + base);
            float4 v;
            v.x = acc[im][in][0] + bvv + xv.x;
            v.y = acc[im][in][1] + bvv + xv.y;
            v.z = acc[im][in][2] + bvv + xv.z;
            v.w = acc[im][in][3] + bvv + xv.w;
            *(float4*)(out + base) = v;
        }
    }
}

// ---------------------------------------------------------------------------
// MERGED PREP: one dispatch does all independent preprocessing.
// (unchanged from round-7 verified version)
// ---------------------------------------------------------------------------
#define NB_TX   1536                      // 16 n-tiles * 12 c-tiles * 8 b
#define NB_WUP  1152                      // 24 c-tiles * 48 k-tiles
#define NB_W2   (DIM * HID / 4 / 256)     // 2304
#define NB_WIN  (KCAT * DIM / 4 / 256)    // 3456
#define NB_WEFF (NEXP * DIM / 256)        // 24
#define NB_PREP (NB_TX + NB_WUP + NB_W2 + NB_WIN + NB_WEFF)   // 8472

__global__ __launch_bounds__(256)
void prep_all(const float* __restrict__ x,  ushort_t* __restrict__ XT,
              const float* __restrict__ wup, ushort_t* __restrict__ Wcat,
              const float* __restrict__ w2,  const float* __restrict__ w1,
              const float* __restrict__ wdn, ushort_t* __restrict__ Win,
              const float* __restrict__ rw,  float* __restrict__ Weff,
              float* __restrict__ accb)
{
    __shared__ ushort_t tile[32][33];
    __shared__ __align__(16) ushort_t t2[64 * 68];
    const int tid = threadIdx.x;
    const int tx = tid & 31, ty = tid >> 5;
    int blk = blockIdx.x;

    if (blk < NB_TX) {                                   // x transpose, 64x64
        const int bx = blk & 15;                         // n-tile
        const int rest = blk >> 4;
        const int by = rest % 12, b = rest / 12;         // c-tile, image
        const int n0 = bx * 64, c0 = by * 64;
#pragma unroll
        for (int j = 0; j < 4; j++) {
            const int idx = j * 256 + tid;               // [0, 1024)
            const int c = idx >> 4, q = idx & 15;
            const float4 v = *(const float4*)(
                x + ((size_t)b * DIM + c0 + c) * NPB + n0 + 4 * q);
            uint2 p;
            p.x = (unsigned)f2b(v.x) | ((unsigned)f2b(v.y) << 16);
            p.y = (unsigned)f2b(v.z) | ((unsigned)f2b(v.w) << 16);
            *(uint2*)&t2[c * 68 + 4 * q] = p;
        }
        __syncthreads();
#pragma unroll
        for (int j = 0; j < 2; j++) {
            const int w = (tid >> 3) + 32 * j;           // token row [0,64)
            const int p = tid & 7;                       // c-chunk
            ushort_t u[8];
#pragma unroll
            for (int cc = 0; cc < 8; cc++) u[cc] = t2[(8 * p + cc) * 68 + w];
            uint4 o;
            o.x = (unsigned)u[0] | ((unsigned)u[1] << 16);
            o.y = (unsigned)u[2] | ((unsigned)u[3] << 16);
            o.z = (unsigned)u[4] | ((unsigned)u[5] << 16);
            o.w = (unsigned)u[6] | ((unsigned)u[7] << 16);
            *(uint4*)&XT[((size_t)b * NPB + n0 + w) * DIM + c0 + 8 * p] = o;
        }
        return;
    }
    blk -= NB_TX;
    if (blk < NB_WUP) {                                  // transpose_wup_cat
        const int bx = blk % 24, by = blk / 24;
        const int c0 = bx * 32, k0 = by * 32;
#pragma unroll
        for (int j = 0; j < 4; j++)
            tile[ty + 8 * j][tx] =
                f2b(wup[(size_t)(k0 + ty + 8 * j) * DIM + c0 + tx]);
        __syncthreads();
#pragma unroll
        for (int j = 0; j < 4; j++)
            Wcat[(size_t)(c0 + ty + 8 * j) * KCAT + HID + k0 + tx] =
                tile[tx][ty + 8 * j];
        return;
    }
    blk -= NB_WUP;
    if (blk < NB_W2) {                                   // w2 -> Wcat[:, :HID]
        const int i = blk * 256 + tid;
        const int c = i / (HID / 4), h = (i % (HID / 4)) * 4;
        const float4 v = *(const float4*)(w2 + (size_t)c * HID + h);
        uint2 p;
        p.x = (unsigned)f2b(v.x) | ((unsigned)f2b(v.y) << 16);
        p.y = (unsigned)f2b(v.z) | ((unsigned)f2b(v.w) << 16);
        *(uint2*)(Wcat + (size_t)c * KCAT + h) = p;
        return;
    }
    blk -= NB_W2;
    if (blk < NB_WIN) {                                  // [w1;wdn] -> Win
        const int i = blk * 256 + tid;
        const int n1 = HID * DIM / 4;
        const float4 v = (i < n1) ? ((const float4*)w1)[i]
                                  : ((const float4*)wdn)[i - n1];
        uint2 p;
        p.x = (unsigned)f2b(v.x) | ((unsigned)f2b(v.y) << 16);
        p.y = (unsigned)f2b(v.z) | ((unsigned)f2b(v.w) << 16);
        ((uint2*)Win)[i] = p;
        return;
    }
    blk -= NB_WIN;
    {                                                    // weff + accb zero
        const int idx = blk * 256 + tid;
        const int e = idx / DIM, c = idx % DIM;
        float s = 0.0f;
        for (int d = 0; d < DLOW; d++)
            s += wdn[(size_t)(e * DLOW + d) * DIM + c] * rw[d];
        Weff[idx] = s;
        if (blk == 0 && tid < 16) accb[tid] = 0.0f;
    }
}

// ---------------------------------------------------------------------------
// Router (all f32): thread t owns one token. logits -> softmax -> top2 -> aux
// ---------------------------------------------------------------------------
__global__ __launch_bounds__(256)
void router_kernel(const float* __restrict__ x, const float* __restrict__ Weff,
                   int* __restrict__ tokE, float* __restrict__ tokW,
                   float* __restrict__ accbuf)
{
    __shared__ float sW[NEXP * DIM];
    __shared__ float sAcc[16];
    const int tid = threadIdx.x;
    for (int i = tid; i < NEXP * DIM; i += 256) sW[i] = Weff[i];
    if (tid < 16) sAcc[tid] = 0.0f;
    __syncthreads();

    const int t = blockIdx.x * 256 + tid;
    const int b = t >> 10, n = t & 1023;
    const float* xb = x + (size_t)b * DIM * NPB + n;

    float lg[8];
#pragma unroll
    for (int e = 0; e < 8; e++) lg[e] = 0.0f;
#pragma unroll 8
    for (int c = 0; c < DIM; c++) {
        const float xv = xb[(size_t)c * NPB];
#pragma unroll
        for (int e = 0; e < 8; e++) lg[e] += xv * sW[e * DIM + c];
    }

    float mx = lg[0];
#pragma unroll
    for (int e = 1; e < 8; e++) mx = fmaxf(mx, lg[e]);
    float pr[8], s = 0.0f;
#pragma unroll
    for (int e = 0; e < 8; e++) { pr[e] = expf(lg[e] - mx); s += pr[e]; }
    const float inv = 1.0f / s;
#pragma unroll
    for (int e = 0; e < 8; e++) pr[e] *= inv;
    int e0 = 0;
#pragma unroll
    for (int e = 1; e < 8; e++) if (pr[e] > pr[e0]) e0 = e;
    int e1 = (e0 == 0) ? 1 : 0;
#pragma unroll
    for (int e = 0; e < 8; e++) if (e != e0 && pr[e] > pr[e1]) e1 = e;
    const float wsum = pr[e0] + pr[e1];
    tokE[2 * t + 0] = e0;  tokE[2 * t + 1] = e1;
    tokW[2 * t + 0] = pr[e0] / wsum;  tokW[2 * t + 1] = pr[e1] / wsum;

#pragma unroll
    for (int e = 0; e < 8; e++) atomicAdd(&sAcc[e], pr[e]);
    atomicAdd(&sAcc[8 + e0], 1.0f);
    atomicAdd(&sAcc[8 + e1], 1.0f);
    __syncthreads();
    if (tid < 16) atomicAdd(&accbuf[tid], sAcc[tid]);
}

// ---------------------------------------------------------------------------
extern "C" void kernel_launch(void* const* d_in, const int* in_sizes, int n_in,
                              void* d_out, int out_size, void* d_ws, size_t ws_size,
                              hipStream_t stream)
{
    (void)in_sizes; (void)n_in; (void)out_size;

    const float* x   = (const float*)d_in[0];
    const float* w1  = (const float*)d_in[1];
    const float* b1  = (const float*)d_in[2];
    const float* w2  = (const float*)d_in[3];
    const float* b2  = (const float*)d_in[4];
    const float* wdn = (const float*)d_in[5];
    const float* rw  = (const float*)d_in[6];
    const float* wup = (const float*)d_in[7];
    float* out = (float*)d_out;

    char* ws = (char*)d_ws;
    size_t off = 0;
    ushort_t* XTbf = (ushort_t*)(ws + off); off += (size_t)NTOK * DIM * 2;   // 12.6 MB
    ushort_t* Win  = (ushort_t*)(ws + off); off += (size_t)KCAT * DIM * 2;   //  7.1 MB
    ushort_t* Wcat = (ushort_t*)(ws + off); off += (size_t)DIM * KCAT * 2;   //  7.1 MB
    float*    Weff = (float*)  (ws + off);  off += (size_t)NEXP * DIM * 4;
    int*      tokE = (int*)    (ws + off);  off += (size_t)NTOK * 2 * 4;
    float*    tokW = (float*)  (ws + off);  off += (size_t)NTOK * 2 * 4;
    float*    accb = (float*)  (ws + off);  off += 256;

    // largest token-chunk that fits (graph-safe: pure function of ws_size)
    int chunk = NTOK / 4;
    if      (ws_size >= off + (size_t)NTOK * KCAT * 2)       chunk = NTOK;
    else if (ws_size >= off + (size_t)(NTOK / 2) * KCAT * 2) chunk = NTOK / 2;
    ushort_t* HU = (ushort_t*)(ws + off);                    // chunk*KCAT bf16

    prep_all<<<NB_PREP, 256, 0, stream>>>(x, XTbf, wup, Wcat, w2, w1, wdn,
                                          Win, rw, Weff, accb);
    router_kernel<<<NTOK / 256, 256, 0, stream>>>(x, Weff, tokE, tokW, accb);

    for (int c = 0; c < NTOK / chunk; c++) {
        const ushort_t* Ax = XTbf + (size_t)c * chunk * DIM;
        const int m_base = c * chunk;
        // HU = [gelu(XT@w1^T + b1) | gelu(XT@wdn^T) * routing weight]
        gemm_in<<<dim3(KCAT / 128, chunk / 128), 256, 0, stream>>>(
            Ax, Win, HU, b1, tokE, tokW, accb, out + (size_t)NTOK * DIM, m_base);
        // out = HU @ Wcat^T + b2 + x
        gemm_out<<<dim3(DIM / 96, chunk / 128), 256, 0, stream>>>(
            HU, Wcat, out, b2, x, m_base);
    }
}

// Round 12
// 272.222 us; speedup vs baseline: 1.1259x; 1.1259x over previous
//
#include <hip/hip_runtime.h>
#include <cstdint>
#include <cmath>

#define DIM   768
#define HID   3072
#define NEXP  8
#define DLOW  192
#define NPB   1024            // tokens per image (32*32)
#define NTOK  8192
#define KD    1536            // NEXP*DLOW
#define KCAT  4608            // HID + KD

typedef unsigned short ushort_t;
typedef short   short8  __attribute__((ext_vector_type(8)));
typedef float   float4v __attribute__((ext_vector_type(4)));

__device__ inline ushort_t f2b(float f) {
    union { float f; unsigned int i; } v; v.f = f;
    unsigned int x = v.i;
    return (ushort_t)((x + 0x7fffu + ((x >> 16) & 1u)) >> 16);   // RNE
}
// tanh-form GELU (max |err| vs erf-GELU ~3e-4, below bf16 rounding of HU)
__device__ inline float gelu_fast(float x) {
    const float z = 1.5957691216057308f * x * __builtin_fmaf(0.044715f * x, x, 1.0f);
    return x * __builtin_amdgcn_rcpf(1.0f + __expf(-z));
}

// async global->LDS, 16 B per lane (global_load_lds_dwordx4)
__device__ __forceinline__ void async_ld16(const ushort_t* g, ushort_t* l) {
    __builtin_amdgcn_global_load_lds(
        (const __attribute__((address_space(1))) void*)g,
        (__attribute__((address_space(3))) void*)l,
        16, 0, 0);
}

// ===========================================================================
// Counted-vmcnt dbuf K-loop (T4) -- verified r9/r10. GEMMs are FROZEN this
// round (r10/r11 schedule A/B was an exact null: 306.47 vs 306.49 us).
// Round 12 targets the never-profiled prep/router latency tails.
// ===========================================================================

// ---------------------------------------------------------------------------
// INPUT GEMM v10 (frozen from r11): 128x128 tile, 256 threads, BK=64,
// m-inner/n-outer XCD mapping (FETCH 48 MB verified), counted-vmcnt dbuf,
// kh-half register prefetch.
// ---------------------------------------------------------------------------
__global__ __launch_bounds__(256, 2)
void gemm_in(const ushort_t* __restrict__ A, const ushort_t* __restrict__ B,
             ushort_t* __restrict__ Cb, const float* __restrict__ bias,
             const int* __restrict__ tokE, const float* __restrict__ tokW,
             const float* __restrict__ accbuf, float* __restrict__ outAux,
             int m_base)
{
    __shared__ __align__(16) ushort_t As[2 * 128 * 64];   // 32 KB (dbuf)
    __shared__ __align__(16) ushort_t Bs[2 * 128 * 64];   // 32 KB (dbuf)

    const int tid  = threadIdx.x;
    const int lane = tid & 63;
    const int wave = tid >> 6;           // 0..3
    const int quad = lane >> 4;
    const int l16  = lane & 15;
    const int wm   = (wave >> 1) * 64;   // 0,64
    const int wn   = (wave & 1) * 64;    // 0,64

    // XCD mapping, m-inner/n-outer (bijective: gridDim.y multiple of 8)
    const int bid = blockIdx.y * gridDim.x + blockIdx.x;
    const int mpx = gridDim.y >> 3;                // m-panels per XCD
    const int xcd = bid & 7;
    const int loc = bid >> 3;                      // [0, 36*mpx)
    const int m0  = (xcd * mpx + loc % mpx) * 128;
    const int n0  = (loc / mpx) * 128;

    float4v acc[4][4];
#pragma unroll
    for (int i = 0; i < 4; i++)
#pragma unroll
        for (int j = 0; j < 4; j++) acc[i][j] = (float4v)0.0f;

    // staging: LDS slot f holds k-group (f&7)^(row&7) of row f>>3
    const ushort_t* ga[4]; ushort_t* la[4];
#pragma unroll
    for (int j = 0; j < 4; j++) {
        const int f = j * 256 + tid;               // [0, 1024)
        const int mm = f >> 3;                     // [0, 128)
        const int gs = ((f & 7) ^ (mm & 7)) * 8;
        ga[j] = A + (size_t)(m0 + mm) * DIM + gs;
        la[j] = &As[f * 8];
    }
    const ushort_t* gb[4]; ushort_t* lb[4];
#pragma unroll
    for (int j = 0; j < 4; j++) {
        const int f = j * 256 + tid;               // [0, 1024)
        const int mm = f >> 3;                     // [0, 128)
        const int gs = ((f & 7) ^ (mm & 7)) * 8;
        gb[j] = B + (size_t)(n0 + mm) * DIM + gs;
        lb[j] = &Bs[f * 8];
    }

    // fragment LDS pointers (buffer 0; buffer 1 = +128*64 elements)
    const ushort_t* pa[2][4]; const ushort_t* pb[2][4];
#pragma unroll
    for (int kh = 0; kh < 2; kh++)
#pragma unroll
        for (int i = 0; i < 4; i++) {
            const int ra = wm + i * 16 + l16;
            pa[kh][i] = &As[ra * 64 + (((quad + 4 * kh) ^ (ra & 7)) * 8)];
            const int rb = wn + i * 16 + l16;
            pb[kh][i] = &Bs[rb * 64 + (((quad + 4 * kh) ^ (rb & 7)) * 8)];
        }

#define STG_I(k0, ao, bo) do {                                              \
    _Pragma("unroll")                                                       \
    for (int j = 0; j < 4; j++) async_ld16(ga[j] + (k0), la[j] + (ao));     \
    _Pragma("unroll")                                                       \
    for (int j = 0; j < 4; j++) async_ld16(gb[j] + (k0), lb[j] + (bo)); } while (0)

    // two kh half-sets of fragment registers (slot reused across tiles)
    short8 afH[2][4], bvH[2][4];

    // prologue: stage tiles 0,1; certify tile 0; read tile0 kh0
    STG_I(0, 0, 0);
    STG_I(64, 128 * 64, 128 * 64);
    asm volatile("s_waitcnt vmcnt(8)" ::: "memory");   // tile0 landed
    __builtin_amdgcn_s_barrier();
    __builtin_amdgcn_sched_barrier(0);
#pragma unroll
    for (int i = 0; i < 4; i++) {
        afH[0][i] = *(const short8*)(pa[0][i]);
        bvH[0][i] = *(const short8*)(pb[0][i]);
    }

#pragma unroll
    for (int t = 0; t < 12; ++t) {
        const int co = (t & 1) * (128 * 64);        // current buffer
        const int no = ((t + 1) & 1) * (128 * 64);  // next buffer

        // 1. read tile-t kh1 (overlaps MFMA kh0 below)
#pragma unroll
        for (int i = 0; i < 4; i++) {
            afH[1][i] = *(const short8*)(pa[1][i] + co);
            bvH[1][i] = *(const short8*)(pb[1][i] + co);
        }
        // 2. MFMA kh0 (regs from previous body / prologue)
#pragma unroll
        for (int im = 0; im < 4; im++)
#pragma unroll
            for (int in = 0; in < 4; in++)
                acc[im][in] = __builtin_amdgcn_mfma_f32_16x16x32_bf16(
                    afH[0][im], bvH[0][in], acc[im][in], 0, 0, 0);
        // 3. all tile-t reads done -> current buffer free
        asm volatile("s_waitcnt lgkmcnt(0)" ::: "memory");
        __builtin_amdgcn_sched_barrier(0);
        __builtin_amdgcn_s_barrier();
        __builtin_amdgcn_sched_barrier(0);
        // 4. stage t+2 into current buffer; retire tile t+1
        if (t + 2 < 12) {
            STG_I((t + 2) * 64, co, co);
            asm volatile("s_waitcnt vmcnt(8)" ::: "memory");
        } else {
            asm volatile("s_waitcnt vmcnt(0)" ::: "memory");
        }
        __builtin_amdgcn_sched_barrier(0);
        __builtin_amdgcn_s_barrier();           // tile t+1 visible to all
        __builtin_amdgcn_sched_barrier(0);
        // 6. read tile-(t+1) kh0 (overlaps MFMA kh1 below)
        if (t + 1 < 12) {
#pragma unroll
            for (int i = 0; i < 4; i++) {
                afH[0][i] = *(const short8*)(pa[0][i] + no);
                bvH[0][i] = *(const short8*)(pb[0][i] + no);
            }
        }
        // 7. MFMA kh1
#pragma unroll
        for (int im = 0; im < 4; im++)
#pragma unroll
            for (int in = 0; in < 4; in++)
                acc[im][in] = __builtin_amdgcn_mfma_f32_16x16x32_bf16(
                    afH[1][im], bvH[1][in], acc[im][in], 0, 0, 0);
    }
#undef STG_I

    if (n0 < HID) {                        // shared-expert hidden: gelu + b1
#pragma unroll
        for (int in = 0; in < 4; in++) {
            const int col = n0 + wn + in * 16 + l16;
            const float bvv = bias[col];
#pragma unroll
            for (int im = 0; im < 4; im++) {
                const int rowl = m0 + wm + im * 16 + quad * 4;
#pragma unroll
                for (int r = 0; r < 4; r++)
                    Cb[(size_t)(rowl + r) * KCAT + col] =
                        f2b(gelu_fast(acc[im][in][r] + bvv));
            }
        }
        if (m_base == 0 && blockIdx.x == 0 && blockIdx.y == 0 && tid == 0) {
            float aux = 0.0f;
            for (int e = 0; e < 8; e++) aux += accbuf[e] * accbuf[8 + e];
            outAux[0] = aux * 8.0f / ((float)NTOK * (float)NTOK);
        }
    } else {                               // feats: gelu * routing weight
        int eidx[4];
#pragma unroll
        for (int in = 0; in < 4; in++)
            eidx[in] = (n0 + wn + in * 16 - HID) / DLOW;   // uniform over l16
#pragma unroll
        for (int im = 0; im < 4; im++) {
            const int rowl = m0 + wm + im * 16 + quad * 4;
#pragma unroll
            for (int r = 0; r < 4; r++) {
                const int g = m_base + rowl + r;
                const int e0 = tokE[2 * g], e1 = tokE[2 * g + 1];
                const float w0 = tokW[2 * g], w1 = tokW[2 * g + 1];
#pragma unroll
                for (int in = 0; in < 4; in++) {
                    const int col = n0 + wn + in * 16 + l16;
                    const float m = (eidx[in] == e0) ? w0
                                  : ((eidx[in] == e1) ? w1 : 0.0f);
                    Cb[(size_t)(rowl + r) * KCAT + col] =
                        f2b(gelu_fast(acc[im][in][r]) * m);
                }
            }
        }
    }
}

// ---------------------------------------------------------------------------
// OUTPUT GEMM v8 (frozen -- session best): 128x96 tile, 4 waves 2Mx2N,
// BK=64 counted-vmcnt dbuf, 56 KB LDS, XCD-chunked swizzle.
//   out[b, col, nn] = HU[m,:].Wcat[col,:] + b2[col] + x[b, col, nn]
// ---------------------------------------------------------------------------
__global__ __launch_bounds__(256, 2)
void gemm_out(const ushort_t* __restrict__ A, const ushort_t* __restrict__ B,
              float* __restrict__ out, const float* __restrict__ bias,
              const float* __restrict__ X, int m_base)
{
    __shared__ __align__(16) ushort_t As[2 * 128 * 64];   // 32 KB (dbuf)
    __shared__ __align__(16) ushort_t Bs[2 * 96 * 64];    // 24 KB (dbuf)

    const int tid  = threadIdx.x;
    const int lane = tid & 63;
    const int wave = tid >> 6;           // 0..3
    const int quad = lane >> 4;
    const int l16  = lane & 15;
    const int wm   = (wave >> 1) * 64;   // 0,64
    const int wn   = (wave & 1) * 48;    // 0,48

    // XCD-chunked swizzle (bijective: grid always a multiple of 8)
    const int nwg = gridDim.x * gridDim.y;
    const int bid = blockIdx.y * gridDim.x + blockIdx.x;
    const int swz = (bid & 7) * (nwg >> 3) + (bid >> 3);
    const int m0  = (swz / gridDim.x) * 128;
    const int n0  = (swz % gridDim.x) * 96;

    float4v acc[4][3];
#pragma unroll
    for (int i = 0; i < 4; i++)
#pragma unroll
        for (int j = 0; j < 3; j++) acc[i][j] = (float4v)0.0f;

    // staging: LDS slot f holds k-group (f&7)^(row&7) of row f>>3
    const ushort_t* ga[4]; ushort_t* la[4];
#pragma unroll
    for (int j = 0; j < 4; j++) {
        const int f = j * 256 + tid;               // [0, 1024)
        const int mm = f >> 3;                     // [0, 128)
        const int gs = ((f & 7) ^ (mm & 7)) * 8;
        ga[j] = A + (size_t)(m0 + mm) * KCAT + gs;
        la[j] = &As[f * 8];
    }
    const ushort_t* gb[3]; ushort_t* lb[3];
#pragma unroll
    for (int j = 0; j < 3; j++) {
        const int f = j * 256 + tid;               // [0, 768)
        const int mm = f >> 3;                     // [0, 96)
        const int gs = ((f & 7) ^ (mm & 7)) * 8;
        gb[j] = B + (size_t)(n0 + mm) * KCAT + gs;
        lb[j] = &Bs[f * 8];
    }

    // fragment LDS pointers (buffer 0; buffer 1 = +const element offset)
    const ushort_t* pa[2][4]; const ushort_t* pb[2][3];
#pragma unroll
    for (int kh = 0; kh < 2; kh++) {
#pragma unroll
        for (int i = 0; i < 4; i++) {
            const int ra = wm + i * 16 + l16;
            pa[kh][i] = &As[ra * 64 + (((quad + 4 * kh) ^ (ra & 7)) * 8)];
        }
#pragma unroll
        for (int i = 0; i < 3; i++) {
            const int rb = wn + i * 16 + l16;
            pb[kh][i] = &Bs[rb * 64 + (((quad + 4 * kh) ^ (rb & 7)) * 8)];
        }
    }

#define STG_O(k0, ao, bo) do {                                              \
    _Pragma("unroll")                                                       \
    for (int j = 0; j < 4; j++) async_ld16(ga[j] + (k0), la[j] + (ao));     \
    _Pragma("unroll")                                                       \
    for (int j = 0; j < 3; j++) async_ld16(gb[j] + (k0), lb[j] + (bo)); } while (0)

#define BODY_O(t, ao, bo) do {                                              \
    short8 af0[4], bv0[3], af1[4], bv1[3];                                  \
    _Pragma("unroll")                                                       \
    for (int i = 0; i < 4; i++) {                                           \
        af0[i] = *(const short8*)(pa[0][i] + (ao));                         \
        af1[i] = *(const short8*)(pa[1][i] + (ao));                         \
    }                                                                       \
    _Pragma("unroll")                                                       \
    for (int i = 0; i < 3; i++) {                                           \
        bv0[i] = *(const short8*)(pb[0][i] + (bo));                         \
        bv1[i] = *(const short8*)(pb[1][i] + (bo));                         \
    }                                                                       \
    asm volatile("s_waitcnt lgkmcnt(0)" ::: "memory");                      \
    __builtin_amdgcn_sched_barrier(0);                                      \
    __builtin_amdgcn_s_barrier();          /* all waves done reading buf */ \
    __builtin_amdgcn_sched_barrier(0);     /* no hoist above barrier */     \
    const bool st_ = (t) + 2 < 72;                                          \
    if (st_) STG_O(((t) + 2) * 64, ao, bo);                                 \
    __builtin_amdgcn_s_setprio(1);                                          \
    _Pragma("unroll")                                                       \
    for (int im = 0; im < 4; im++)                                          \
        _Pragma("unroll")                                                   \
        for (int in = 0; in < 3; in++)                                      \
            acc[im][in] = __builtin_amdgcn_mfma_f32_16x16x32_bf16(          \
                af0[im], bv0[in], acc[im][in], 0, 0, 0);                    \
    _Pragma("unroll")                                                       \
    for (int im = 0; im < 4; im++)                                          \
        _Pragma("unroll")                                                   \
        for (int in = 0; in < 3; in++)                                      \
            acc[im][in] = __builtin_amdgcn_mfma_f32_16x16x32_bf16(          \
                af1[im], bv1[in], acc[im][in], 0, 0, 0);                    \
    __builtin_amdgcn_s_setprio(0);                                          \
    if (st_) asm volatile("s_waitcnt vmcnt(7)" ::: "memory");               \
    else     asm volatile("s_waitcnt vmcnt(0)" ::: "memory");               \
    __builtin_amdgcn_sched_barrier(0);                                      \
    __builtin_amdgcn_s_barrier();          /* next tile globally ready */   \
    __builtin_amdgcn_sched_barrier(0);                                      \
} while (0)

    // prologue: stage tiles 0,1; wait own tile-0 loads; sync
    STG_O(0, 0, 0);
    STG_O(64, 128 * 64, 96 * 64);
    asm volatile("s_waitcnt vmcnt(7)" ::: "memory");
    __builtin_amdgcn_s_barrier();
    __builtin_amdgcn_sched_barrier(0);

    for (int tt = 0; tt < 72; tt += 2) {
        BODY_O(tt, 0, 0);
        BODY_O(tt + 1, 128 * 64, 96 * 64);
    }
#undef STG_O
#undef BODY_O

#pragma unroll
    for (int in = 0; in < 3; in++) {
        const int col = n0 + wn + in * 16 + l16;
        const float bvv = bias[col];
#pragma unroll
        for (int im = 0; im < 4; im++) {
            const int grow = m_base + m0 + wm + im * 16 + quad * 4;
            const int bb = grow >> 10, nn = grow & 1023;
            const size_t base = ((size_t)bb * DIM + col) * NPB + nn;
            const float4 xv = *(const float4*)(X + base);
            float4 v;
            v.x = acc[im][in][0] + bvv + xv.x;
            v.y = acc[im][in][1] + bvv + xv.y;
            v.z = acc[im][in][2] + bvv + xv.z;
            v.w = acc[im][in][3] + bvv + xv.w;
            *(float4*)(out + base) = v;
        }
    }
}

// ---------------------------------------------------------------------------
// MERGED PREP: WEFF blocks now FIRST (they are 24 latency-bound blocks of
// 192 strided loads -- as the tail of 8472 blocks they ran on an idle
// machine after everything else; first, they overlap the transposes).
//   [0, 24)          : Weff fold (+accb zero)
//   [24, +1536)      : x f32 [B,C,N] -> XTbf bf16 [T,C]  (64x64 vectorized)
//   [.., +1152)      : w_up f32 -> Wcat[:, HID:] bf16    (transpose)
//   [.., +2304+3456) : w2 -> Wcat[:, :HID]; [w1;wdn] -> Win (flat cvt)
// ---------------------------------------------------------------------------
#define NB_TX   1536                      // 16 n-tiles * 12 c-tiles * 8 b
#define NB_WUP  1152                      // 24 c-tiles * 48 k-tiles
#define NB_W2   (DIM * HID / 4 / 256)     // 2304
#define NB_WIN  (KCAT * DIM / 4 / 256)    // 3456
#define NB_WEFF (NEXP * DIM / 256)        // 24
#define NB_PREP (NB_WEFF + NB_TX + NB_WUP + NB_W2 + NB_WIN)   // 8472

__global__ __launch_bounds__(256)
void prep_all(const float* __restrict__ x,  ushort_t* __restrict__ XT,
              const float* __restrict__ wup, ushort_t* __restrict__ Wcat,
              const float* __restrict__ w2,  const float* __restrict__ w1,
              const float* __restrict__ wdn, ushort_t* __restrict__ Win,
              const float* __restrict__ rw,  float* __restrict__ Weff,
              float* __restrict__ accb)
{
    __shared__ ushort_t tile[32][33];
    __shared__ __align__(16) ushort_t t2[64 * 68];
    const int tid = threadIdx.x;
    const int tx = tid & 31, ty = tid >> 5;
    int blk = blockIdx.x;

    if (blk < NB_WEFF) {                                 // weff + accb zero
        const int idx = blk * 256 + tid;
        const int e = idx / DIM, c = idx % DIM;
        float s = 0.0f;
#pragma unroll 8
        for (int d = 0; d < DLOW; d++)
            s += wdn[(size_t)(e * DLOW + d) * DIM + c] * rw[d];
        Weff[idx] = s;
        if (blk == 0 && tid < 16) accb[tid] = 0.0f;
        return;
    }
    blk -= NB_WEFF;
    if (blk < NB_TX) {                                   // x transpose, 64x64
        const int bx = blk & 15;                         // n-tile
        const int rest = blk >> 4;
        const int by = rest % 12, b = rest / 12;         // c-tile, image
        const int n0 = bx * 64, c0 = by * 64;
#pragma unroll
        for (int j = 0; j < 4; j++) {
            const int idx = j * 256 + tid;               // [0, 1024)
            const int c = idx >> 4, q = idx & 15;
            const float4 v = *(const float4*)(
                x + ((size_t)b * DIM + c0 + c) * NPB + n0 + 4 * q);
            uint2 p;
            p.x = (unsigned)f2b(v.x) | ((unsigned)f2b(v.y) << 16);
            p.y = (unsigned)f2b(v.z) | ((unsigned)f2b(v.w) << 16);
            *(uint2*)&t2[c * 68 + 4 * q] = p;
        }
        __syncthreads();
#pragma unroll
        for (int j = 0; j < 2; j++) {
            const int w = (tid >> 3) + 32 * j;           // token row [0,64)
            const int p = tid & 7;                       // c-chunk
            ushort_t u[8];
#pragma unroll
            for (int cc = 0; cc < 8; cc++) u[cc] = t2[(8 * p + cc) * 68 + w];
            uint4 o;
            o.x = (unsigned)u[0] | ((unsigned)u[1] << 16);
            o.y = (unsigned)u[2] | ((unsigned)u[3] << 16);
            o.z = (unsigned)u[4] | ((unsigned)u[5] << 16);
            o.w = (unsigned)u[6] | ((unsigned)u[7] << 16);
            *(uint4*)&XT[((size_t)b * NPB + n0 + w) * DIM + c0 + 8 * p] = o;
        }
        return;
    }
    blk -= NB_TX;
    if (blk < NB_WUP) {                                  // transpose_wup_cat
        const int bx = blk % 24, by = blk / 24;
        const int c0 = bx * 32, k0 = by * 32;
#pragma unroll
        for (int j = 0; j < 4; j++)
            tile[ty + 8 * j][tx] =
                f2b(wup[(size_t)(k0 + ty + 8 * j) * DIM + c0 + tx]);
        __syncthreads();
#pragma unroll
        for (int j = 0; j < 4; j++)
            Wcat[(size_t)(c0 + ty + 8 * j) * KCAT + HID + k0 + tx] =
                tile[tx][ty + 8 * j];
        return;
    }
    blk -= NB_WUP;
    if (blk < NB_W2) {                                   // w2 -> Wcat[:, :HID]
        const int i = blk * 256 + tid;
        const int c = i / (HID / 4), h = (i % (HID / 4)) * 4;
        const float4 v = *(const float4*)(w2 + (size_t)c * HID + h);
        uint2 p;
        p.x = (unsigned)f2b(v.x) | ((unsigned)f2b(v.y) << 16);
        p.y = (unsigned)f2b(v.z) | ((unsigned)f2b(v.w) << 16);
        *(uint2*)(Wcat + (size_t)c * KCAT + h) = p;
        return;
    }
    blk -= NB_W2;
    {                                                    // [w1;wdn] -> Win
        const int i = blk * 256 + tid;
        const int n1 = HID * DIM / 4;
        const float4 v = (i < n1) ? ((const float4*)w1)[i]
                                  : ((const float4*)wdn)[i - n1];
        uint2 p;
        p.x = (unsigned)f2b(v.x) | ((unsigned)f2b(v.y) << 16);
        p.y = (unsigned)f2b(v.z) | ((unsigned)f2b(v.w) << 16);
        ((uint2*)Win)[i] = p;
    }
}

// ---------------------------------------------------------------------------
// Router v2: 64 tokens/block, 4 c-quarter threads per token (256 thr).
// Serial strided-load chain per thread: 768 -> 192 (4x less exposed
// latency); grid 32 -> 128 blocks (4x CU spread). LDS partial-reduce,
// then lane q==0 finalizes softmax/top2 (identical formulas).
// ---------------------------------------------------------------------------
__global__ __launch_bounds__(256)
void router_kernel(const float* __restrict__ x, const float* __restrict__ Weff,
                   int* __restrict__ tokE, float* __restrict__ tokW,
                   float* __restrict__ accbuf)
{
    __shared__ float sW[NEXP * DIM];        // 24 KB
    __shared__ float red[4][64][NEXP];      //  8 KB
    __shared__ float sAcc[16];
    const int tid = threadIdx.x;
    for (int i = tid; i < NEXP * DIM; i += 256) sW[i] = Weff[i];
    if (tid < 16) sAcc[tid] = 0.0f;
    __syncthreads();

    const int s = tid & 63;                 // token slot in block
    const int q = tid >> 6;                 // c-quarter 0..3
    const int t = blockIdx.x * 64 + s;
    const int b = t >> 10, n = t & 1023;
    const float* xb = x + (size_t)b * DIM * NPB + n;

    float lg[8];
#pragma unroll
    for (int e = 0; e < 8; e++) lg[e] = 0.0f;
    const int c0 = q * 192;
#pragma unroll 8
    for (int c = c0; c < c0 + 192; c++) {
        const float xv = xb[(size_t)c * NPB];
#pragma unroll
        for (int e = 0; e < 8; e++) lg[e] += xv * sW[e * DIM + c];
    }
#pragma unroll
    for (int e = 0; e < 8; e++) red[q][s][e] = lg[e];
    __syncthreads();

    if (q == 0) {
#pragma unroll
        for (int e = 0; e < 8; e++)
            lg[e] = red[0][s][e] + red[1][s][e] + red[2][s][e] + red[3][s][e];

        float mx = lg[0];
#pragma unroll
        for (int e = 1; e < 8; e++) mx = fmaxf(mx, lg[e]);
        float pr[8], sm = 0.0f;
#pragma unroll
        for (int e = 0; e < 8; e++) { pr[e] = expf(lg[e] - mx); sm += pr[e]; }
        const float inv = 1.0f / sm;
#pragma unroll
        for (int e = 0; e < 8; e++) pr[e] *= inv;
        int e0 = 0;
#pragma unroll
        for (int e = 1; e < 8; e++) if (pr[e] > pr[e0]) e0 = e;
        int e1 = (e0 == 0) ? 1 : 0;
#pragma unroll
        for (int e = 0; e < 8; e++) if (e != e0 && pr[e] > pr[e1]) e1 = e;
        const float wsum = pr[e0] + pr[e1];
        tokE[2 * t + 0] = e0;  tokE[2 * t + 1] = e1;
        tokW[2 * t + 0] = pr[e0] / wsum;  tokW[2 * t + 1] = pr[e1] / wsum;

#pragma unroll
        for (int e = 0; e < 8; e++) atomicAdd(&sAcc[e], pr[e]);
        atomicAdd(&sAcc[8 + e0], 1.0f);
        atomicAdd(&sAcc[8 + e1], 1.0f);
    }
    __syncthreads();
    if (tid < 16) atomicAdd(&accbuf[tid], sAcc[tid]);
}

// ---------------------------------------------------------------------------
extern "C" void kernel_launch(void* const* d_in, const int* in_sizes, int n_in,
                              void* d_out, int out_size, void* d_ws, size_t ws_size,
                              hipStream_t stream)
{
    (void)in_sizes; (void)n_in; (void)out_size;

    const float* x   = (const float*)d_in[0];
    const float* w1  = (const float*)d_in[1];
    const float* b1  = (const float*)d_in[2];
    const float* w2  = (const float*)d_in[3];
    const float* b2  = (const float*)d_in[4];
    const float* wdn = (const float*)d_in[5];
    const float* rw  = (const float*)d_in[6];
    const float* wup = (const float*)d_in[7];
    float* out = (float*)d_out;

    char* ws = (char*)d_ws;
    size_t off = 0;
    ushort_t* XTbf = (ushort_t*)(ws + off); off += (size_t)NTOK * DIM * 2;   // 12.6 MB
    ushort_t* Win  = (ushort_t*)(ws + off); off += (size_t)KCAT * DIM * 2;   //  7.1 MB
    ushort_t* Wcat = (ushort_t*)(ws + off); off += (size_t)DIM * KCAT * 2;   //  7.1 MB
    float*    Weff = (float*)  (ws + off);  off += (size_t)NEXP * DIM * 4;
    int*      tokE = (int*)    (ws + off);  off += (size_t)NTOK * 2 * 4;
    float*    tokW = (float*)  (ws + off);  off += (size_t)NTOK * 2 * 4;
    float*    accb = (float*)  (ws + off);  off += 256;

    // largest token-chunk that fits (graph-safe: pure function of ws_size)
    int chunk = NTOK / 4;
    if      (ws_size >= off + (size_t)NTOK * KCAT * 2)       chunk = NTOK;
    else if (ws_size >= off + (size_t)(NTOK / 2) * KCAT * 2) chunk = NTOK / 2;
    ushort_t* HU = (ushort_t*)(ws + off);                    // chunk*KCAT bf16

    prep_all<<<NB_PREP, 256, 0, stream>>>(x, XTbf, wup, Wcat, w2, w1, wdn,
                                          Win, rw, Weff, accb);
    router_kernel<<<NTOK / 64, 256, 0, stream>>>(x, Weff, tokE, tokW, accb);

    for (int c = 0; c < NTOK / chunk; c++) {
        const ushort_t* Ax = XTbf + (size_t)c * chunk * DIM;
        const int m_base = c * chunk;
        // HU = [gelu(XT@w1^T + b1) | gelu(XT@wdn^T) * routing weight]
        gemm_in<<<dim3(KCAT / 128, chunk / 128), 256, 0, stream>>>(
            Ax, Win, HU, b1, tokE, tokW, accb, out + (size_t)NTOK * DIM, m_base);
        // out = HU @ Wcat^T + b2 + x
        gemm_out<<<dim3(DIM / 96, chunk / 128), 256, 0, stream>>>(
            HU, Wcat, out, b2, x, m_base);
    }
}